// Round 2
// baseline (10197.732 us; speedup 1.0000x reference)
//
#include <hip/hip_runtime.h>
#include <cstdint>
#include <cstddef>

// ---------------------------------------------------------------------------
// RNNModel: 2-layer bidirectional GRU (B=64, T=1000, H=256) + FC(512->61) +
// length-gather.
// Round 2: fix suspected ws_size overflow (round-1 abort):
//  - xb/h1/h2 share one 65.5 MB pool (liveness-disjoint)
//  - gi stored fp32 if ws_size allows (~464 MB peak) else bf16 (~267 MB peak)
//  - robust lengths decode (int32 vs int64 buffer)
// ---------------------------------------------------------------------------

typedef __attribute__((ext_vector_type(8))) __bf16 bf16x8;
typedef __attribute__((ext_vector_type(4))) float f32x4;
typedef __attribute__((ext_vector_type(4))) unsigned int u32x4;

#define AS1 __attribute__((address_space(1)))
#define AS3 __attribute__((address_space(3)))

__device__ __forceinline__ void async_ld16(const void* g, void* l) {
  // global -> LDS direct copy, 16B/lane; LDS dest = wave-uniform base + lane*16
  __builtin_amdgcn_global_load_lds((const AS1 unsigned int*)g,
                                   (AS3 unsigned int*)l, 16, 0, 0);
}

__device__ __forceinline__ f32x4 mfma16(u32x4 a, u32x4 b, f32x4 c) {
  return __builtin_amdgcn_mfma_f32_16x16x32_bf16(
      __builtin_bit_cast(bf16x8, a), __builtin_bit_cast(bf16x8, b), c, 0, 0, 0);
}

__device__ __forceinline__ unsigned short f2b(float f) {  // f32 -> bf16 RNE
  unsigned int u = __float_as_uint(f);
  u += 0x7fffu + ((u >> 16) & 1u);
  return (unsigned short)(u >> 16);
}
__device__ __forceinline__ float b2f(unsigned short s) {
  return __uint_as_float(((unsigned int)s) << 16);
}
__device__ __forceinline__ float gload(const float* p, size_t i) { return p[i]; }
__device__ __forceinline__ float gload(const unsigned short* p, size_t i) { return b2f(p[i]); }
__device__ __forceinline__ void gstore(float* p, size_t i, float v) { p[i] = v; }
__device__ __forceinline__ void gstore(unsigned short* p, size_t i, float v) { p[i] = f2b(v); }

__device__ __forceinline__ float sigm(float x) { return 1.0f / (1.0f + __expf(-x)); }
__device__ __forceinline__ float tanh_(float x) { return 1.0f - 2.0f / (1.0f + __expf(2.0f * x)); }

// ---------------------------------------------------------------------------
__global__ void cast_bf16_kernel(const float* __restrict__ src,
                                 unsigned short* __restrict__ dst, int n) {
  const int i = blockIdx.x * 256 + threadIdx.x;
  if (i < n) dst[i] = f2b(src[i]);
}

// batch [B,T,8,40] -> x [T,B,320] bf16, x[t,b,f*8+c] = batch[b,t,c,f]
__global__ void transpose_x_kernel(const float* __restrict__ batch,
                                   unsigned short* __restrict__ xb) {
  const int t = blockIdx.x, b = blockIdx.y, i = threadIdx.x;  // block 320
  const float v = batch[((size_t)b * 1000 + t) * 320 + (i & 7) * 40 + (i >> 3)];
  xb[((size_t)t * 64 + b) * 320 + i] = f2b(v);
}

// ---------------------------------------------------------------------------
// C[M,N] = A[M,K](bf16) @ W[N,K](bf16)^T + bias[N]. CT = float or ushort(bf16).
// 128x128 tile, BK=32, 256 thr. LDS tiles in fragment order (m97 recipe):
// chunk s: row = ((s>>6)<<4)|(s&15), k8 = (s>>4)&3; LDS 16B-unit index = s.
template <typename CT>
__global__ __launch_bounds__(256) void gemm_bt_kernel(
    const unsigned short* __restrict__ A, const unsigned short* __restrict__ W,
    const float* __restrict__ bias, CT* __restrict__ C, int M, int N, int K) {
  __shared__ __align__(16) unsigned short As[4096];
  __shared__ __align__(16) unsigned short Bs[4096];
  const int tid = threadIdx.x;
  const int lane = tid & 63;
  const int wv = tid >> 6;
  const int mBase = blockIdx.x * 128;
  const int nBase = blockIdx.y * 128;

  const int s0 = tid, s1 = tid + 256;
  const int r0 = ((s0 >> 6) << 4) | (s0 & 15), c0 = ((s0 >> 4) & 3) * 8;
  const int r1 = ((s1 >> 6) << 4) | (s1 & 15), c1 = ((s1 >> 4) & 3) * 8;

  const unsigned short* Arow0 = A + (size_t)(mBase + r0) * K + c0;
  const unsigned short* Arow1 = A + (size_t)(mBase + r1) * K + c1;
  const unsigned short* Wrow0 = W + (size_t)(nBase + r0) * K + c0;
  const unsigned short* Wrow1 = W + (size_t)(nBase + r1) * K + c1;

  char* lA = (char*)As;
  char* lB = (char*)Bs;
  char* dstA0 = lA + wv * 1024;
  char* dstA1 = lA + 4096 + wv * 1024;
  char* dstB0 = lB + wv * 1024;
  char* dstB1 = lB + 4096 + wv * 1024;

  f32x4 acc[4][4] = {};
  const int mh = (wv >> 1) * 64, nh = (wv & 1) * 64;
  const u32x4* As4 = (const u32x4*)As;
  const u32x4* Bs4 = (const u32x4*)Bs;

  for (int k0 = 0; k0 < K; k0 += 32) {
    __syncthreads();
    async_ld16(Arow0 + k0, dstA0);
    async_ld16(Arow1 + k0, dstA1);
    async_ld16(Wrow0 + k0, dstB0);
    async_ld16(Wrow1 + k0, dstB1);
    __syncthreads();
    u32x4 a[4], b[4];
#pragma unroll
    for (int mt = 0; mt < 4; ++mt) a[mt] = As4[((mh >> 4) + mt) * 64 + lane];
#pragma unroll
    for (int nt = 0; nt < 4; ++nt) b[nt] = Bs4[((nh >> 4) + nt) * 64 + lane];
#pragma unroll
    for (int mt = 0; mt < 4; ++mt)
#pragma unroll
      for (int nt = 0; nt < 4; ++nt)
        acc[mt][nt] = mfma16(a[mt], b[nt], acc[mt][nt]);
  }
#pragma unroll
  for (int nt = 0; nt < 4; ++nt) {
    const int n = nBase + nh + nt * 16 + (lane & 15);
    const float bn = bias[n];
#pragma unroll
    for (int mt = 0; mt < 4; ++mt) {
      const int mrow = mBase + mh + mt * 16 + ((lane >> 4) << 2);
#pragma unroll
      for (int r = 0; r < 4; ++r)
        gstore(C, (size_t)(mrow + r) * N + n, acc[mt][nt][r] + bn);
    }
  }
}

// ---------------------------------------------------------------------------
// One GRU layer, both directions. grid=8: dir=bx&1, samples (bx>>1)*16..+15.
// 1024 thr = 16 waves. Per step: gh[16,768] = h_bf16[16,256] @ Whh^T via MFMA
// (wave wv owns 3 n-tiles; W streamed from L2 as B-frags), then gates.
// h fp32 in regs (thread owns h[s=si+4i][j=tid&255]); bf16 copy in LDS = A-op.
template <typename GT>
__global__ __launch_bounds__(1024) void gru_layer_kernel(
    const GT* __restrict__ gi,               // [T*B][1536] (b_ih folded in)
    const unsigned short* __restrict__ whh,  // [2][768][256] bf16
    const float* __restrict__ bhh,           // [2][768]
    unsigned short* __restrict__ hout) {     // [T*B][512] bf16
  __shared__ __align__(16) unsigned short hbf[16][264];  // +8 pad
  __shared__ __align__(16) float gh[16][780];            // +12 pad
  const int tid = threadIdx.x;
  const int lane = tid & 63;
  const int wv = tid >> 6;  // 0..15
  const int dir = blockIdx.x & 1;
  const int sb = (blockIdx.x >> 1) * 16;
  const int j = tid & 255;
  const int si = tid >> 8;  // 0..3

  float hreg[4] = {0.f, 0.f, 0.f, 0.f};
#pragma unroll
  for (int i = 0; i < 4; ++i) hbf[si + i * 4][j] = 0;

  const float bh_r = bhh[dir * 768 + j];
  const float bh_z = bhh[dir * 768 + 256 + j];
  const float bh_n = bhh[dir * 768 + 512 + j];

  // B-frag base: gate row g = wv*48 + (lane&15), k = (lane>>4)*8
  const unsigned short* wl = whh + (size_t)dir * 768 * 256 +
                             (size_t)(wv * 48 + (lane & 15)) * 256 +
                             ((lane >> 4) * 8);
  // A-frag base: sample = lane&15, k = (lane>>4)*8 (+kt*32)
  const char* habase = (const char*)hbf + (lane & 15) * 528 + ((lane >> 4) << 4);
  const int srow = (lane >> 4) * 4;

  __syncthreads();

  for (int step = 0; step < 1000; ++step) {
    const int t = dir ? (999 - step) : step;
    // prefetch this step's gi values (HBM latency hides under MFMA phase)
    float p_ir[4], p_iz[4], p_in[4];
#pragma unroll
    for (int i = 0; i < 4; ++i) {
      const int s = si + i * 4;
      const size_t gib = ((size_t)t * 64 + (sb + s)) * 1536 + dir * 768 + j;
      p_ir[i] = gload(gi, gib);
      p_iz[i] = gload(gi, gib + 256);
      p_in[i] = gload(gi, gib + 512);
    }
    u32x4 a[8];
#pragma unroll
    for (int kt = 0; kt < 8; ++kt) a[kt] = *(const u32x4*)(habase + kt * 64);
#pragma unroll
    for (int ntd = 0; ntd < 3; ++ntd) {
      f32x4 acc = {0.f, 0.f, 0.f, 0.f};
#pragma unroll
      for (int kt = 0; kt < 8; ++kt) {
        u32x4 bfrag = *(const u32x4*)(wl + ntd * (16 * 256) + kt * 32);
        acc = mfma16(a[kt], bfrag, acc);
      }
      const int gcol = (wv * 3 + ntd) * 16 + (lane & 15);
#pragma unroll
      for (int r = 0; r < 4; ++r) gh[srow + r][gcol] = acc[r];
    }
    __syncthreads();
#pragma unroll
    for (int i = 0; i < 4; ++i) {
      const int s = si + i * 4;
      const float r = sigm(p_ir[i] + gh[s][j] + bh_r);
      const float z = sigm(p_iz[i] + gh[s][256 + j] + bh_z);
      const float n = tanh_(p_in[i] + r * (gh[s][512 + j] + bh_n));
      const float h = (1.f - z) * n + z * hreg[i];
      hreg[i] = h;
      const unsigned short hb = f2b(h);
      hbf[s][j] = hb;
      hout[((size_t)t * 64 + (sb + s)) * 512 + dir * 256 + j] = hb;
    }
    __syncthreads();
  }
}

// ---------------------------------------------------------------------------
// lengths may arrive as int32 or int64 (little-endian). True lengths are in
// [500,1000] (never 0), so int64 shows as [len,0,len,0,...] in int32 view.
__global__ void prefix_kernel(const int* __restrict__ raw,
                              int* __restrict__ pref, int* __restrict__ lens) {
  if (threadIdx.x == 0) {
    const int stride = (raw[1] == 0 && raw[3] == 0 && raw[5] == 0) ? 2 : 1;
    int a = 0;
    for (int b = 0; b < 64; ++b) {
      const int L = raw[b * stride];
      pref[b] = a;
      lens[b] = L;
      a += L;
    }
  }
}

// out[pref[b]+t][o] = h2[t,b] . fc_w[o] + fc_b[o], for t < len[b].
__global__ __launch_bounds__(256) void fc_kernel(
    const unsigned short* __restrict__ h2, const unsigned short* __restrict__ fcw,
    const float* __restrict__ fcb, const int* __restrict__ lens,
    const int* __restrict__ pref, float* __restrict__ out) {
  __shared__ __align__(16) unsigned short hrow[4][512];
  const int b = blockIdx.y;
  const int sub = threadIdx.x >> 6, lane = threadIdx.x & 63;
  const int t = blockIdx.x * 4 + sub;
  *(u32x4*)&hrow[sub][lane * 8] =
      *(const u32x4*)&h2[((size_t)t * 64 + b) * 512 + lane * 8];
  __syncthreads();
  const int len = lens[b];
  if (lane < 61 && t < len) {
    float acc = fcb[lane];
    const unsigned short* wr = fcw + (size_t)lane * 512;
#pragma unroll 4
    for (int k = 0; k < 512; k += 8) {
      u32x4 w4 = *(const u32x4*)(wr + k);
      u32x4 h4 = *(const u32x4*)(&hrow[sub][k]);
#pragma unroll
      for (int q = 0; q < 4; ++q) {
        acc += __uint_as_float(w4[q] << 16) * __uint_as_float(h4[q] << 16);
        acc += __uint_as_float(w4[q] & 0xffff0000u) * __uint_as_float(h4[q] & 0xffff0000u);
      }
    }
    out[((size_t)pref[b] + t) * 61 + lane] = acc;
  }
}

// ---------------------------------------------------------------------------
template <typename GT>
static void run_pipeline(const float* batch, const int* lengths_raw,
                         const float* w_ih_l0, const float* w_hh_l0,
                         const float* b_ih_l0, const float* b_hh_l0,
                         const float* w_ih_l1, const float* w_hh_l1,
                         const float* b_ih_l1, const float* b_hh_l1,
                         const float* fc_w, const float* fc_b, float* out,
                         char* ws, hipStream_t stream) {
  size_t off = 0;
  auto alloc = [&](size_t bytes) -> char* {
    char* p = ws + off;
    off += (bytes + 255) & ~(size_t)255;
    return p;
  };
  // shared pool: xb (41 MB) -> h1 (66 MB) -> h2 (66 MB), liveness-disjoint
  char* pool = alloc((size_t)64000 * 512 * 2);
  unsigned short* xb = (unsigned short*)pool;
  unsigned short* h1 = (unsigned short*)pool;
  unsigned short* h2 = (unsigned short*)pool;
  GT*             gi   = (GT*)alloc((size_t)64000 * 1536 * sizeof(GT));
  unsigned short* wih0 = (unsigned short*)alloc((size_t)1536 * 320 * 2);
  unsigned short* wih1 = (unsigned short*)alloc((size_t)1536 * 512 * 2);
  unsigned short* whh0 = (unsigned short*)alloc((size_t)1536 * 256 * 2);
  unsigned short* whh1 = (unsigned short*)alloc((size_t)1536 * 256 * 2);
  unsigned short* fcwb = (unsigned short*)alloc((size_t)61 * 512 * 2);
  int*            pref = (int*)alloc(256);
  int*            lens = (int*)alloc(256);

  auto cast = [&](const float* s, unsigned short* d, int n) {
    cast_bf16_kernel<<<dim3((n + 255) / 256), dim3(256), 0, stream>>>(s, d, n);
  };
  cast(w_ih_l0, wih0, 2 * 768 * 320);
  cast(w_hh_l0, whh0, 2 * 768 * 256);
  cast(w_ih_l1, wih1, 2 * 768 * 512);
  cast(w_hh_l1, whh1, 2 * 768 * 256);
  cast(fc_w,    fcwb, 61 * 512);

  transpose_x_kernel<<<dim3(1000, 64), dim3(320), 0, stream>>>(batch, xb);

  gemm_bt_kernel<GT><<<dim3(500, 12), dim3(256), 0, stream>>>(
      xb, wih0, b_ih_l0, gi, 64000, 1536, 320);
  gru_layer_kernel<GT><<<dim3(8), dim3(1024), 0, stream>>>(gi, whh0, b_hh_l0, h1);
  gemm_bt_kernel<GT><<<dim3(500, 12), dim3(256), 0, stream>>>(
      h1, wih1, b_ih_l1, gi, 64000, 1536, 512);
  gru_layer_kernel<GT><<<dim3(8), dim3(1024), 0, stream>>>(gi, whh1, b_hh_l1, h2);

  prefix_kernel<<<dim3(1), dim3(64), 0, stream>>>(lengths_raw, pref, lens);
  fc_kernel<<<dim3(250, 64), dim3(256), 0, stream>>>(h2, fcwb, fc_b, lens, pref, out);
}

extern "C" void kernel_launch(void* const* d_in, const int* in_sizes, int n_in,
                              void* d_out, int out_size, void* d_ws, size_t ws_size,
                              hipStream_t stream) {
  (void)in_sizes; (void)n_in; (void)out_size;
  const float* batch   = (const float*)d_in[0];
  const int*   lengths = (const int*)d_in[1];
  const float* w_ih_l0 = (const float*)d_in[2];
  const float* w_hh_l0 = (const float*)d_in[3];
  const float* b_ih_l0 = (const float*)d_in[4];
  const float* b_hh_l0 = (const float*)d_in[5];
  const float* w_ih_l1 = (const float*)d_in[6];
  const float* w_hh_l1 = (const float*)d_in[7];
  const float* b_ih_l1 = (const float*)d_in[8];
  const float* b_hh_l1 = (const float*)d_in[9];
  const float* fc_w    = (const float*)d_in[10];
  const float* fc_b    = (const float*)d_in[11];
  float* out = (float*)d_out;
  char* ws = (char*)d_ws;

  // peak: pool 65.6 MB + gi + weights ~4.3 MB (+ padding)
  const size_t NEED_FP32 = 470000000ull;  // gi fp32 = 393.2 MB
  if (ws_size >= NEED_FP32) {
    run_pipeline<float>(batch, lengths, w_ih_l0, w_hh_l0, b_ih_l0, b_hh_l0,
                        w_ih_l1, w_hh_l1, b_ih_l1, b_hh_l1, fc_w, fc_b, out,
                        ws, stream);
  } else {
    run_pipeline<unsigned short>(batch, lengths, w_ih_l0, w_hh_l0, b_ih_l0,
                                 b_hh_l0, w_ih_l1, w_hh_l1, b_ih_l1, b_hh_l1,
                                 fc_w, fc_b, out, ws, stream);
  }
}

// Round 3
// 6736.082 us; speedup vs baseline: 1.5139x; 1.5139x over previous
//
#include <hip/hip_runtime.h>
#include <cstdint>
#include <cstddef>

// ---------------------------------------------------------------------------
// RNNModel: 2-layer bidirectional GRU (B=64, T=1000, H=256) + FC(512->61) +
// length-gather.
// Round 3: gru_fast_kernel — W_hh CU-resident (30 frags/wave in VGPRs +
// 18 frags/wave in LDS, 144 KB), in-register gate combine (wave owns the
// r/z/n tiles of its own hidden-unit slice), lgkm-only barriers.
// Fallback to round-2 gru_layer_kernel if >64KB dynamic LDS is unsupported.
// ---------------------------------------------------------------------------

typedef __attribute__((ext_vector_type(8))) __bf16 bf16x8;
typedef __attribute__((ext_vector_type(4))) float f32x4;
typedef __attribute__((ext_vector_type(4))) unsigned int u32x4;

#define AS1 __attribute__((address_space(1)))
#define AS3 __attribute__((address_space(3)))

__device__ __forceinline__ void async_ld16(const void* g, void* l) {
  __builtin_amdgcn_global_load_lds((const AS1 unsigned int*)g,
                                   (AS3 unsigned int*)l, 16, 0, 0);
}

__device__ __forceinline__ f32x4 mfma16(u32x4 a, u32x4 b, f32x4 c) {
  return __builtin_amdgcn_mfma_f32_16x16x32_bf16(
      __builtin_bit_cast(bf16x8, a), __builtin_bit_cast(bf16x8, b), c, 0, 0, 0);
}

__device__ __forceinline__ unsigned short f2b(float f) {  // f32 -> bf16 RNE
  unsigned int u = __float_as_uint(f);
  u += 0x7fffu + ((u >> 16) & 1u);
  return (unsigned short)(u >> 16);
}
__device__ __forceinline__ float b2f(unsigned short s) {
  return __uint_as_float(((unsigned int)s) << 16);
}
__device__ __forceinline__ float gload(const float* p, size_t i) { return p[i]; }
__device__ __forceinline__ float gload(const unsigned short* p, size_t i) { return b2f(p[i]); }
__device__ __forceinline__ void gstore(float* p, size_t i, float v) { p[i] = v; }
__device__ __forceinline__ void gstore(unsigned short* p, size_t i, float v) { p[i] = f2b(v); }

__device__ __forceinline__ float sigm(float x) { return 1.0f / (1.0f + __expf(-x)); }
__device__ __forceinline__ float tanh_(float x) { return 1.0f - 2.0f / (1.0f + __expf(2.0f * x)); }

// lgkm-only barrier: do NOT drain vmcnt (hout stores / gi prefetch stay in
// flight). Only LDS ordering is needed across the barrier.
__device__ __forceinline__ void lds_barrier() {
  asm volatile("" ::: "memory");
  __builtin_amdgcn_s_waitcnt(0xC07F);  // vmcnt=63, expcnt=7, lgkmcnt=0
  __builtin_amdgcn_s_barrier();
  asm volatile("" ::: "memory");
}

// ---------------------------------------------------------------------------
__global__ void cast_bf16_kernel(const float* __restrict__ src,
                                 unsigned short* __restrict__ dst, int n) {
  const int i = blockIdx.x * 256 + threadIdx.x;
  if (i < n) dst[i] = f2b(src[i]);
}

// batch [B,T,8,40] -> x [T,B,320] bf16, x[t,b,f*8+c] = batch[b,t,c,f]
__global__ void transpose_x_kernel(const float* __restrict__ batch,
                                   unsigned short* __restrict__ xb) {
  const int t = blockIdx.x, b = blockIdx.y, i = threadIdx.x;  // block 320
  const float v = batch[((size_t)b * 1000 + t) * 320 + (i & 7) * 40 + (i >> 3)];
  xb[((size_t)t * 64 + b) * 320 + i] = f2b(v);
}

// ---------------------------------------------------------------------------
// C[M,N] = A[M,K](bf16) @ W[N,K](bf16)^T + bias[N]. CT = float or ushort(bf16).
// 128x128 tile, BK=32, 256 thr, m97 recipe (fragment-ordered LDS).
template <typename CT>
__global__ __launch_bounds__(256) void gemm_bt_kernel(
    const unsigned short* __restrict__ A, const unsigned short* __restrict__ W,
    const float* __restrict__ bias, CT* __restrict__ C, int M, int N, int K) {
  __shared__ __align__(16) unsigned short As[4096];
  __shared__ __align__(16) unsigned short Bs[4096];
  const int tid = threadIdx.x;
  const int lane = tid & 63;
  const int wv = tid >> 6;
  const int mBase = blockIdx.x * 128;
  const int nBase = blockIdx.y * 128;

  const int s0 = tid, s1 = tid + 256;
  const int r0 = ((s0 >> 6) << 4) | (s0 & 15), c0 = ((s0 >> 4) & 3) * 8;
  const int r1 = ((s1 >> 6) << 4) | (s1 & 15), c1 = ((s1 >> 4) & 3) * 8;

  const unsigned short* Arow0 = A + (size_t)(mBase + r0) * K + c0;
  const unsigned short* Arow1 = A + (size_t)(mBase + r1) * K + c1;
  const unsigned short* Wrow0 = W + (size_t)(nBase + r0) * K + c0;
  const unsigned short* Wrow1 = W + (size_t)(nBase + r1) * K + c1;

  char* lA = (char*)As;
  char* lB = (char*)Bs;
  char* dstA0 = lA + wv * 1024;
  char* dstA1 = lA + 4096 + wv * 1024;
  char* dstB0 = lB + wv * 1024;
  char* dstB1 = lB + 4096 + wv * 1024;

  f32x4 acc[4][4] = {};
  const int mh = (wv >> 1) * 64, nh = (wv & 1) * 64;
  const u32x4* As4 = (const u32x4*)As;
  const u32x4* Bs4 = (const u32x4*)Bs;

  for (int k0 = 0; k0 < K; k0 += 32) {
    __syncthreads();
    async_ld16(Arow0 + k0, dstA0);
    async_ld16(Arow1 + k0, dstA1);
    async_ld16(Wrow0 + k0, dstB0);
    async_ld16(Wrow1 + k0, dstB1);
    __syncthreads();
    u32x4 a[4], b[4];
#pragma unroll
    for (int mt = 0; mt < 4; ++mt) a[mt] = As4[((mh >> 4) + mt) * 64 + lane];
#pragma unroll
    for (int nt = 0; nt < 4; ++nt) b[nt] = Bs4[((nh >> 4) + nt) * 64 + lane];
#pragma unroll
    for (int mt = 0; mt < 4; ++mt)
#pragma unroll
      for (int nt = 0; nt < 4; ++nt)
        acc[mt][nt] = mfma16(a[mt], b[nt], acc[mt][nt]);
  }
#pragma unroll
  for (int nt = 0; nt < 4; ++nt) {
    const int n = nBase + nh + nt * 16 + (lane & 15);
    const float bn = bias[n];
#pragma unroll
    for (int mt = 0; mt < 4; ++mt) {
      const int mrow = mBase + mh + mt * 16 + ((lane >> 4) << 2);
#pragma unroll
      for (int r = 0; r < 4; ++r)
        gstore(C, (size_t)(mrow + r) * N + n, acc[mt][nt][r] + bn);
    }
  }
}

// ---------------------------------------------------------------------------
// FAST GRU layer. grid=8: dir=bx&1, samples sb=(bx>>1)*16..+15. 512 thr = 8
// waves, one WG per CU (forced by 152 KB LDS). Wave w owns hidden units
// u0=32w+c, u1=u0+16 (c=lane&15) via gate tiles {32w,32w+16,256+32w,...}.
// W_hh frags: kt 0..4 in VGPRs (30 frags = 120 regs), kt 5..7 in LDS (18
// frags/wave = 144 KB). h state fp32 in regs; bf16 A-operand copy in LDS.
template <typename GT>
__global__ __launch_bounds__(512, 2) void gru_fast_kernel(
    const GT* __restrict__ gi,               // [T*B][1536] (b_ih folded in)
    const unsigned short* __restrict__ whh,  // [2][768][256] bf16
    const float* __restrict__ bhh,           // [2][768]
    unsigned short* __restrict__ hout) {     // [T*B][512] bf16
  extern __shared__ __align__(16) char smem[];
  char* wlds = smem;                 // 8 waves * 18 frags * 1024 B = 147456
  char* hl = smem + 147456;          // h bf16 [16][264] = 8448 B (stride 528)
  const int tid = threadIdx.x;
  const int lane = tid & 63;
  const int w = tid >> 6;   // 0..7
  const int c = lane & 15;  // unit col (B-frag n) / sample row (A-frag m)
  const int q = lane >> 4;  // 0..3
  const int dir = blockIdx.x & 1;
  const int sb = (blockIdx.x >> 1) * 16;
  const int u0 = 32 * w + c, u1 = u0 + 16;

  for (int i = tid; i < 16 * 264; i += 512) ((unsigned short*)hl)[i] = 0;

  const float* bh = bhh + dir * 768;
  const float bhr0 = bh[u0], bhr1 = bh[u1];
  const float bhz0 = bh[256 + u0], bhz1 = bh[256 + u1];
  const float bhn0 = bh[512 + u0], bhn1 = bh[512 + u1];

  // preload W: frag (nt,kt): B[n = gb[nt]+c][k = kt*32 + q*8 + 0..7]
  const unsigned short* wd = whh + (size_t)dir * 196608 + (size_t)c * 256 + q * 8;
  const int gb[6] = {32 * w,       32 * w + 16,       256 + 32 * w,
                     256 + 32 * w + 16, 512 + 32 * w, 512 + 32 * w + 16};
  u32x4 wreg[6][5];
#pragma unroll
  for (int nt = 0; nt < 6; ++nt) {
    const unsigned short* p = wd + (size_t)gb[nt] * 256;
#pragma unroll
    for (int kt = 0; kt < 5; ++kt) wreg[nt][kt] = *(const u32x4*)(p + kt * 32);
#pragma unroll
    for (int kk = 0; kk < 3; ++kk) {
      u32x4 tmp = *(const u32x4*)(p + (5 + kk) * 32);
      *(u32x4*)(wlds + (((w * 18 + nt * 3 + kk) << 10) + lane * 16)) = tmp;
    }
  }
  float hr0[4] = {0.f, 0.f, 0.f, 0.f}, hr1[4] = {0.f, 0.f, 0.f, 0.f};
  __syncthreads();

  const char* habase = hl + c * 528 + q * 16;  // A-frag: sample=c, k=q*8

  for (int step = 0; step < 1000; ++step) {
    const int t = dir ? (999 - step) : step;
    u32x4 a[8];
#pragma unroll
    for (int kt = 0; kt < 8; ++kt) a[kt] = *(const u32x4*)(habase + kt * 64);
    lds_barrier();  // all A-reads done before any h_lds rewrite

    // gi prefetch (consumed in gate phase; latency hides under MFMAs)
    float p0[4], p1[4], p2[4], p3[4], p4[4], p5[4];
    const size_t base = ((size_t)t * 64 + sb) * 1536 + (size_t)dir * 768;
#pragma unroll
    for (int r = 0; r < 4; ++r) {
      const size_t rb = base + (size_t)(q * 4 + r) * 1536;
      p0[r] = gload(gi, rb + u0);
      p1[r] = gload(gi, rb + u1);
      p2[r] = gload(gi, rb + 256 + u0);
      p3[r] = gload(gi, rb + 256 + u1);
      p4[r] = gload(gi, rb + 512 + u0);
      p5[r] = gload(gi, rb + 512 + u1);
    }

    f32x4 acc[6] = {};
#pragma unroll
    for (int kt = 0; kt < 5; ++kt)
#pragma unroll
      for (int nt = 0; nt < 6; ++nt)
        acc[nt] = mfma16(a[kt], wreg[nt][kt], acc[nt]);
#pragma unroll
    for (int kk = 0; kk < 3; ++kk) {
      u32x4 bf[6];
#pragma unroll
      for (int nt = 0; nt < 6; ++nt)
        bf[nt] = *(const u32x4*)(wlds + (((w * 18 + nt * 3 + kk) << 10) + lane * 16));
#pragma unroll
      for (int nt = 0; nt < 6; ++nt)
        acc[nt] = mfma16(a[5 + kk], bf[nt], acc[nt]);
    }

    // in-register gate combine: acc[0/2/4]=r/z/n of u0, acc[1/3/5]=of u1;
    // C-layout row = q*4 + reg -> sample s
    unsigned short* hls = (unsigned short*)hl;
#pragma unroll
    for (int r = 0; r < 4; ++r) {
      const int s = q * 4 + r;
      const float rr0 = sigm(p0[r] + acc[0][r] + bhr0);
      const float zz0 = sigm(p2[r] + acc[2][r] + bhz0);
      const float nn0 = tanh_(p4[r] + rr0 * (acc[4][r] + bhn0));
      const float h0 = (1.f - zz0) * nn0 + zz0 * hr0[r];
      hr0[r] = h0;
      const float rr1 = sigm(p1[r] + acc[1][r] + bhr1);
      const float zz1 = sigm(p3[r] + acc[3][r] + bhz1);
      const float nn1 = tanh_(p5[r] + rr1 * (acc[5][r] + bhn1));
      const float h1 = (1.f - zz1) * nn1 + zz1 * hr1[r];
      hr1[r] = h1;
      const unsigned short hb0 = f2b(h0), hb1 = f2b(h1);
      hls[s * 264 + u0] = hb0;
      hls[s * 264 + u1] = hb1;
      const size_t ob = ((size_t)t * 64 + sb + s) * 512 + (size_t)dir * 256;
      hout[ob + u0] = hb0;
      hout[ob + u1] = hb1;
    }
    lds_barrier();  // h_lds writes visible before next step's A-reads
  }
}

// ---------------------------------------------------------------------------
// LEGACY GRU layer (round-2, passing) — fallback if big dynamic LDS fails.
template <typename GT>
__global__ __launch_bounds__(1024) void gru_layer_kernel(
    const GT* __restrict__ gi, const unsigned short* __restrict__ whh,
    const float* __restrict__ bhh, unsigned short* __restrict__ hout) {
  __shared__ __align__(16) unsigned short hbf[16][264];
  __shared__ __align__(16) float gh[16][780];
  const int tid = threadIdx.x;
  const int lane = tid & 63;
  const int wv = tid >> 6;
  const int dir = blockIdx.x & 1;
  const int sb = (blockIdx.x >> 1) * 16;
  const int j = tid & 255;
  const int si = tid >> 8;

  float hreg[4] = {0.f, 0.f, 0.f, 0.f};
#pragma unroll
  for (int i = 0; i < 4; ++i) hbf[si + i * 4][j] = 0;

  const float bh_r = bhh[dir * 768 + j];
  const float bh_z = bhh[dir * 768 + 256 + j];
  const float bh_n = bhh[dir * 768 + 512 + j];

  const unsigned short* wl = whh + (size_t)dir * 768 * 256 +
                             (size_t)(wv * 48 + (lane & 15)) * 256 +
                             ((lane >> 4) * 8);
  const char* habase = (const char*)hbf + (lane & 15) * 528 + ((lane >> 4) << 4);
  const int srow = (lane >> 4) * 4;

  __syncthreads();

  for (int step = 0; step < 1000; ++step) {
    const int t = dir ? (999 - step) : step;
    float p_ir[4], p_iz[4], p_in[4];
#pragma unroll
    for (int i = 0; i < 4; ++i) {
      const int s = si + i * 4;
      const size_t gib = ((size_t)t * 64 + (sb + s)) * 1536 + dir * 768 + j;
      p_ir[i] = gload(gi, gib);
      p_iz[i] = gload(gi, gib + 256);
      p_in[i] = gload(gi, gib + 512);
    }
    u32x4 a[8];
#pragma unroll
    for (int kt = 0; kt < 8; ++kt) a[kt] = *(const u32x4*)(habase + kt * 64);
#pragma unroll
    for (int ntd = 0; ntd < 3; ++ntd) {
      f32x4 acc = {0.f, 0.f, 0.f, 0.f};
#pragma unroll
      for (int kt = 0; kt < 8; ++kt) {
        u32x4 bfrag = *(const u32x4*)(wl + ntd * (16 * 256) + kt * 32);
        acc = mfma16(a[kt], bfrag, acc);
      }
      const int gcol = (wv * 3 + ntd) * 16 + (lane & 15);
#pragma unroll
      for (int r = 0; r < 4; ++r) gh[srow + r][gcol] = acc[r];
    }
    __syncthreads();
#pragma unroll
    for (int i = 0; i < 4; ++i) {
      const int s = si + i * 4;
      const float r = sigm(p_ir[i] + gh[s][j] + bh_r);
      const float z = sigm(p_iz[i] + gh[s][256 + j] + bh_z);
      const float n = tanh_(p_in[i] + r * (gh[s][512 + j] + bh_n));
      const float h = (1.f - z) * n + z * hreg[i];
      hreg[i] = h;
      const unsigned short hb = f2b(h);
      hbf[s][j] = hb;
      hout[((size_t)t * 64 + (sb + s)) * 512 + dir * 256 + j] = hb;
    }
    __syncthreads();
  }
}

// ---------------------------------------------------------------------------
__global__ void prefix_kernel(const int* __restrict__ raw,
                              int* __restrict__ pref, int* __restrict__ lens) {
  if (threadIdx.x == 0) {
    const int stride = (raw[1] == 0 && raw[3] == 0 && raw[5] == 0) ? 2 : 1;
    int a = 0;
    for (int b = 0; b < 64; ++b) {
      const int L = raw[b * stride];
      pref[b] = a;
      lens[b] = L;
      a += L;
    }
  }
}

__global__ __launch_bounds__(256) void fc_kernel(
    const unsigned short* __restrict__ h2, const unsigned short* __restrict__ fcw,
    const float* __restrict__ fcb, const int* __restrict__ lens,
    const int* __restrict__ pref, float* __restrict__ out) {
  __shared__ __align__(16) unsigned short hrow[4][512];
  const int b = blockIdx.y;
  const int sub = threadIdx.x >> 6, lane = threadIdx.x & 63;
  const int t = blockIdx.x * 4 + sub;
  *(u32x4*)&hrow[sub][lane * 8] =
      *(const u32x4*)&h2[((size_t)t * 64 + b) * 512 + lane * 8];
  __syncthreads();
  const int len = lens[b];
  if (lane < 61 && t < len) {
    float acc = fcb[lane];
    const unsigned short* wr = fcw + (size_t)lane * 512;
#pragma unroll 4
    for (int k = 0; k < 512; k += 8) {
      u32x4 w4 = *(const u32x4*)(wr + k);
      u32x4 h4 = *(const u32x4*)(&hrow[sub][k]);
#pragma unroll
      for (int q = 0; q < 4; ++q) {
        acc += __uint_as_float(w4[q] << 16) * __uint_as_float(h4[q] << 16);
        acc += __uint_as_float(w4[q] & 0xffff0000u) * __uint_as_float(h4[q] & 0xffff0000u);
      }
    }
    out[((size_t)pref[b] + t) * 61 + lane] = acc;
  }
}

// ---------------------------------------------------------------------------
template <typename GT>
static void run_pipeline(const float* batch, const int* lengths_raw,
                         const float* w_ih_l0, const float* w_hh_l0,
                         const float* b_ih_l0, const float* b_hh_l0,
                         const float* w_ih_l1, const float* w_hh_l1,
                         const float* b_ih_l1, const float* b_hh_l1,
                         const float* fc_w, const float* fc_b, float* out,
                         char* ws, hipStream_t stream) {
  size_t off = 0;
  auto alloc = [&](size_t bytes) -> char* {
    char* p = ws + off;
    off += (bytes + 255) & ~(size_t)255;
    return p;
  };
  char* pool = alloc((size_t)64000 * 512 * 2);  // xb/h1/h2 liveness-disjoint
  unsigned short* xb = (unsigned short*)pool;
  unsigned short* h1 = (unsigned short*)pool;
  unsigned short* h2 = (unsigned short*)pool;
  GT*             gi   = (GT*)alloc((size_t)64000 * 1536 * sizeof(GT));
  unsigned short* wih0 = (unsigned short*)alloc((size_t)1536 * 320 * 2);
  unsigned short* wih1 = (unsigned short*)alloc((size_t)1536 * 512 * 2);
  unsigned short* whh0 = (unsigned short*)alloc((size_t)1536 * 256 * 2);
  unsigned short* whh1 = (unsigned short*)alloc((size_t)1536 * 256 * 2);
  unsigned short* fcwb = (unsigned short*)alloc((size_t)61 * 512 * 2);
  int*            pref = (int*)alloc(256);
  int*            lens = (int*)alloc(256);

  auto cast = [&](const float* s, unsigned short* d, int n) {
    cast_bf16_kernel<<<dim3((n + 255) / 256), dim3(256), 0, stream>>>(s, d, n);
  };
  cast(w_ih_l0, wih0, 2 * 768 * 320);
  cast(w_hh_l0, whh0, 2 * 768 * 256);
  cast(w_ih_l1, wih1, 2 * 768 * 512);
  cast(w_hh_l1, whh1, 2 * 768 * 256);
  cast(fc_w,    fcwb, 61 * 512);

  transpose_x_kernel<<<dim3(1000, 64), dim3(320), 0, stream>>>(batch, xb);

  const int GRU_LDS = 147456 + 16 * 264 * 2;  // 155904 B
  const bool big_lds =
      hipFuncSetAttribute(reinterpret_cast<const void*>(gru_fast_kernel<GT>),
                          hipFuncAttributeMaxDynamicSharedMemorySize,
                          GRU_LDS) == hipSuccess;

  auto gru = [&](GT* g, unsigned short* w, const float* b, unsigned short* h) {
    if (big_lds)
      gru_fast_kernel<GT><<<dim3(8), dim3(512), GRU_LDS, stream>>>(g, w, b, h);
    else
      gru_layer_kernel<GT><<<dim3(8), dim3(1024), 0, stream>>>(g, w, b, h);
  };

  gemm_bt_kernel<GT><<<dim3(500, 12), dim3(256), 0, stream>>>(
      xb, wih0, b_ih_l0, gi, 64000, 1536, 320);
  gru(gi, whh0, b_hh_l0, h1);
  gemm_bt_kernel<GT><<<dim3(500, 12), dim3(256), 0, stream>>>(
      h1, wih1, b_ih_l1, gi, 64000, 1536, 512);
  gru(gi, whh1, b_hh_l1, h2);

  prefix_kernel<<<dim3(1), dim3(64), 0, stream>>>(lengths_raw, pref, lens);
  fc_kernel<<<dim3(250, 64), dim3(256), 0, stream>>>(h2, fcwb, fc_b, lens, pref, out);
}

extern "C" void kernel_launch(void* const* d_in, const int* in_sizes, int n_in,
                              void* d_out, int out_size, void* d_ws, size_t ws_size,
                              hipStream_t stream) {
  (void)in_sizes; (void)n_in; (void)out_size;
  const float* batch   = (const float*)d_in[0];
  const int*   lengths = (const int*)d_in[1];
  const float* w_ih_l0 = (const float*)d_in[2];
  const float* w_hh_l0 = (const float*)d_in[3];
  const float* b_ih_l0 = (const float*)d_in[4];
  const float* b_hh_l0 = (const float*)d_in[5];
  const float* w_ih_l1 = (const float*)d_in[6];
  const float* w_hh_l1 = (const float*)d_in[7];
  const float* b_ih_l1 = (const float*)d_in[8];
  const float* b_hh_l1 = (const float*)d_in[9];
  const float* fc_w    = (const float*)d_in[10];
  const float* fc_b    = (const float*)d_in[11];
  float* out = (float*)d_out;
  char* ws = (char*)d_ws;

  const size_t NEED_FP32 = 470000000ull;  // gi fp32 = 393.2 MB + pool + weights
  if (ws_size >= NEED_FP32) {
    run_pipeline<float>(batch, lengths, w_ih_l0, w_hh_l0, b_ih_l0, b_hh_l0,
                        w_ih_l1, w_hh_l1, b_ih_l1, b_hh_l1, fc_w, fc_b, out,
                        ws, stream);
  } else {
    run_pipeline<unsigned short>(batch, lengths, w_ih_l0, w_hh_l0, b_ih_l0,
                                 b_hh_l0, w_ih_l1, w_hh_l1, b_ih_l1, b_hh_l1,
                                 fc_w, fc_b, out, ws, stream);
  }
}

// Round 4
// 4795.057 us; speedup vs baseline: 2.1267x; 1.4048x over previous
//
#include <hip/hip_runtime.h>
#include <cstdint>
#include <cstddef>

// ---------------------------------------------------------------------------
// RNNModel: 2-layer bidirectional GRU (B=64, T=1000, H=256) + FC(512->61) +
// length-gather.
// Round 4:
//  - W_hh frags pinned in VGPRs via empty asm (36/wave) + 12/wave in LDS
//  - exp2-prescaled gates: W/bias rows scaled by -log2e (r,z) / +2log2e (n)
//    => sigm = rcp(1+exp2(x)), tanh = fma(-2, rcp(1+exp2(y)), 1)
//  - b_ih + b_hh(r,z) fused into GEMM bias; only b_hh(n) stays in GRU kernel
//  - h-LDS row stride 576 B (conflict-free A-frag reads)
//  - moving gi/hout pointers (one add per step instead of full recompute)
// ---------------------------------------------------------------------------

typedef __attribute__((ext_vector_type(8))) __bf16 bf16x8;
typedef __attribute__((ext_vector_type(4))) float f32x4;
typedef __attribute__((ext_vector_type(4))) unsigned int u32x4;

#define AS1 __attribute__((address_space(1)))
#define AS3 __attribute__((address_space(3)))

#define LOG2E 1.44269504089f
#define SRZ  (-1.44269504089f)   // scale for r,z rows
#define SN   (2.88539008177f)    // scale for n rows

__device__ __forceinline__ void async_ld16(const void* g, void* l) {
  __builtin_amdgcn_global_load_lds((const AS1 unsigned int*)g,
                                   (AS3 unsigned int*)l, 16, 0, 0);
}

__device__ __forceinline__ f32x4 mfma16(u32x4 a, u32x4 b, f32x4 c) {
  return __builtin_amdgcn_mfma_f32_16x16x32_bf16(
      __builtin_bit_cast(bf16x8, a), __builtin_bit_cast(bf16x8, b), c, 0, 0, 0);
}

__device__ __forceinline__ unsigned short f2b(float f) {  // f32 -> bf16 RNE
  unsigned int u = __float_as_uint(f);
  u += 0x7fffu + ((u >> 16) & 1u);
  return (unsigned short)(u >> 16);
}
__device__ __forceinline__ float b2f(unsigned short s) {
  return __uint_as_float(((unsigned int)s) << 16);
}
__device__ __forceinline__ float gload(const float* p, size_t i) { return p[i]; }
__device__ __forceinline__ float gload(const unsigned short* p, size_t i) { return b2f(p[i]); }
__device__ __forceinline__ void gstore(float* p, size_t i, float v) { p[i] = v; }
__device__ __forceinline__ void gstore(unsigned short* p, size_t i, float v) { p[i] = f2b(v); }

// pre-scaled gate helpers (inputs already multiplied by SRZ / SN)
__device__ __forceinline__ float sigm2(float xs) {  // sigma(x), xs = -log2e*x
  return __builtin_amdgcn_rcpf(1.0f + __builtin_amdgcn_exp2f(xs));
}
__device__ __forceinline__ float tanh2(float ys) {  // tanh(y), ys = 2log2e*y
  return __builtin_fmaf(-2.0f,
      __builtin_amdgcn_rcpf(1.0f + __builtin_amdgcn_exp2f(ys)), 1.0f);
}

// lgkm-only barrier: don't drain vmcnt (stores/prefetch stay in flight)
__device__ __forceinline__ void lds_barrier() {
  asm volatile("" ::: "memory");
  __builtin_amdgcn_s_waitcnt(0xC07F);  // vmcnt=63, expcnt=7, lgkmcnt=0
  __builtin_amdgcn_s_barrier();
  asm volatile("" ::: "memory");
}

// ---------------------------------------------------------------------------
__global__ void cast_bf16_kernel(const float* __restrict__ src,
                                 unsigned short* __restrict__ dst, int n) {
  const int i = blockIdx.x * 256 + threadIdx.x;
  if (i < n) dst[i] = f2b(src[i]);
}

// weight cast with per-gate-row exp2 prescale. rows: [0,512) r,z ; [512,768) n
__global__ void cast_w_kernel(const float* __restrict__ src,
                              unsigned short* __restrict__ dst, int n,
                              int in_dim) {
  const int i = blockIdx.x * 256 + threadIdx.x;
  if (i < n) {
    const int row = (i / in_dim) % 768;
    const float s = (row < 512) ? SRZ : SN;
    dst[i] = f2b(s * src[i]);
  }
}

// fused GEMM bias: scaled (b_ih + b_hh) for r,z rows; scaled b_ih for n rows
__global__ void bias_fuse_kernel(const float* __restrict__ bih,
                                 const float* __restrict__ bhh,
                                 float* __restrict__ fb) {
  const int n = blockIdx.x * 256 + threadIdx.x;  // 0..1535
  if (n < 1536) {
    const int dir = n >> 9 >> 1 ? 1 : (n / 768);  // n/768
    const int rr = n - dir * 768;
    const float s = (rr < 512) ? SRZ : SN;
    float v = bih[dir * 768 + rr];
    if (rr < 512) v += bhh[dir * 768 + rr];
    fb[n] = s * v;
  }
}

// batch [B,T,8,40] -> x [T,B,320] bf16, x[t,b,f*8+c] = batch[b,t,c,f]
__global__ void transpose_x_kernel(const float* __restrict__ batch,
                                   unsigned short* __restrict__ xb) {
  const int t = blockIdx.x, b = blockIdx.y, i = threadIdx.x;  // block 320
  const float v = batch[((size_t)b * 1000 + t) * 320 + (i & 7) * 40 + (i >> 3)];
  xb[((size_t)t * 64 + b) * 320 + i] = f2b(v);
}

// ---------------------------------------------------------------------------
// C[M,N] = A[M,K](bf16) @ W[N,K](bf16)^T + bias[N]. CT = float or ushort(bf16).
// 128x128 tile, BK=32, 256 thr, m97 recipe (fragment-ordered LDS).
template <typename CT>
__global__ __launch_bounds__(256) void gemm_bt_kernel(
    const unsigned short* __restrict__ A, const unsigned short* __restrict__ W,
    const float* __restrict__ bias, CT* __restrict__ C, int M, int N, int K) {
  __shared__ __align__(16) unsigned short As[4096];
  __shared__ __align__(16) unsigned short Bs[4096];
  const int tid = threadIdx.x;
  const int lane = tid & 63;
  const int wv = tid >> 6;
  const int mBase = blockIdx.x * 128;
  const int nBase = blockIdx.y * 128;

  const int s0 = tid, s1 = tid + 256;
  const int r0 = ((s0 >> 6) << 4) | (s0 & 15), c0 = ((s0 >> 4) & 3) * 8;
  const int r1 = ((s1 >> 6) << 4) | (s1 & 15), c1 = ((s1 >> 4) & 3) * 8;

  const unsigned short* Arow0 = A + (size_t)(mBase + r0) * K + c0;
  const unsigned short* Arow1 = A + (size_t)(mBase + r1) * K + c1;
  const unsigned short* Wrow0 = W + (size_t)(nBase + r0) * K + c0;
  const unsigned short* Wrow1 = W + (size_t)(nBase + r1) * K + c1;

  char* lA = (char*)As;
  char* lB = (char*)Bs;
  char* dstA0 = lA + wv * 1024;
  char* dstA1 = lA + 4096 + wv * 1024;
  char* dstB0 = lB + wv * 1024;
  char* dstB1 = lB + 4096 + wv * 1024;

  f32x4 acc[4][4] = {};
  const int mh = (wv >> 1) * 64, nh = (wv & 1) * 64;
  const u32x4* As4 = (const u32x4*)As;
  const u32x4* Bs4 = (const u32x4*)Bs;

  for (int k0 = 0; k0 < K; k0 += 32) {
    __syncthreads();
    async_ld16(Arow0 + k0, dstA0);
    async_ld16(Arow1 + k0, dstA1);
    async_ld16(Wrow0 + k0, dstB0);
    async_ld16(Wrow1 + k0, dstB1);
    __syncthreads();
    u32x4 a[4], b[4];
#pragma unroll
    for (int mt = 0; mt < 4; ++mt) a[mt] = As4[((mh >> 4) + mt) * 64 + lane];
#pragma unroll
    for (int nt = 0; nt < 4; ++nt) b[nt] = Bs4[((nh >> 4) + nt) * 64 + lane];
#pragma unroll
    for (int mt = 0; mt < 4; ++mt)
#pragma unroll
      for (int nt = 0; nt < 4; ++nt)
        acc[mt][nt] = mfma16(a[mt], b[nt], acc[mt][nt]);
  }
#pragma unroll
  for (int nt = 0; nt < 4; ++nt) {
    const int n = nBase + nh + nt * 16 + (lane & 15);
    const float bn = bias[n];
#pragma unroll
    for (int mt = 0; mt < 4; ++mt) {
      const int mrow = mBase + mh + mt * 16 + ((lane >> 4) << 2);
#pragma unroll
      for (int r = 0; r < 4; ++r)
        gstore(C, (size_t)(mrow + r) * N + n, acc[mt][nt][r] + bn);
    }
  }
}

// ---------------------------------------------------------------------------
// FAST GRU layer. grid=8: dir=bx&1, samples sb=(bx>>1)*16. 512 thr = 8 waves.
// Wave w owns units [32w, 32w+32): unit tiles j=0,1 (u=32w+16j+c), gate rows
// g*256+32w+16j. W frags (j,g,kt): kt 0..5 pinned in VGPRs (36 frags=144 regs,
// asm pin defeats rematerialization), kt 6,7 in LDS (12/wave, 96 KB).
// h-LDS stride 576 B => A-frag granule = (4c+q) mod 32 (2-way, free).
// Gates use exp2-prescaled inputs (see cast_w/bias_fuse).
template <typename GT>
__global__ __launch_bounds__(512, 2) void gru_fast_kernel(
    const GT* __restrict__ gi,               // [T*B][1536] prescaled, bias folded
    const unsigned short* __restrict__ whh,  // [2][768][256] bf16 prescaled
    const float* __restrict__ bhh,           // [2][768] raw
    unsigned short* __restrict__ hout) {     // [T*B][512] bf16
  extern __shared__ __align__(16) char smem[];
  char* wlds = smem;           // 8 waves * 12 frags * 1024 B = 98304
  char* hl = smem + 98304;     // h bf16 [16][288] stride 576 B = 9216 B
  const int tid = threadIdx.x;
  const int lane = tid & 63;
  const int w = tid >> 6;   // 0..7
  const int c = lane & 15;
  const int q = lane >> 4;  // 0..3
  const int dir = blockIdx.x & 1;
  const int sb = (blockIdx.x >> 1) * 16;

  for (int i = tid; i < 4608; i += 512) ((unsigned short*)hl)[i] = 0;

  const int u0 = 32 * w + c;  // j=0 unit; j=1 is u0+16
  const float bhn0 = SN * bhh[dir * 768 + 512 + u0];
  const float bhn1 = SN * bhh[dir * 768 + 512 + u0 + 16];

  // ---- W preload: frag (j,g,kt): row = g*256 + 32w + 16j + c, k = kt*32+q*8
  const unsigned short* wb =
      whh + (size_t)dir * 196608 + (size_t)u0 * 256 + q * 8;
  u32x4 wv[2][3][6];
#pragma unroll
  for (int j = 0; j < 2; ++j)
#pragma unroll
    for (int g = 0; g < 3; ++g) {
      const unsigned short* p = wb + (size_t)(g * 256 + 16 * j) * 256;
#pragma unroll
      for (int kt = 0; kt < 6; ++kt) wv[j][g][kt] = *(const u32x4*)(p + kt * 32);
#pragma unroll
      for (int kk = 0; kk < 2; ++kk) {
        u32x4 tmp = *(const u32x4*)(p + (6 + kk) * 32);
        *(u32x4*)(wlds + (((w * 12 + (j * 3 + g) * 2 + kk) << 10) + lane * 16)) = tmp;
      }
    }
  // pin: make each frag an opaque asm def -> cannot be rematerialized in-loop
#pragma unroll
  for (int j = 0; j < 2; ++j)
#pragma unroll
    for (int g = 0; g < 3; ++g)
#pragma unroll
      for (int kt = 0; kt < 6; ++kt)
        asm volatile("" : "+v"(wv[j][g][kt]));

  float h0[4] = {0.f, 0.f, 0.f, 0.f}, h1[4] = {0.f, 0.f, 0.f, 0.f};
  __syncthreads();

  // moving pointers (element units), lane-constant column offsets folded in
  const int t0 = dir ? 999 : 0;
  const GT* gp = gi + ((size_t)t0 * 64 + sb) * 1536 + dir * 768 + u0;
  unsigned short* hp = hout + ((size_t)t0 * 64 + sb) * 512 + dir * 256 + u0;
  const ptrdiff_t gstep = (dir ? -1 : 1) * (ptrdiff_t)(64 * 1536);
  const ptrdiff_t hstep = (dir ? -1 : 1) * (ptrdiff_t)(64 * 512);

  const char* habase = hl + c * 576 + q * 16;  // A-frag: sample=c, k=q*8 (+kt*64)
  const int hw0 = q * 4 * 288 + u0;            // h-LDS write base (u16 units)

  for (int step = 0; step < 1000; ++step) {
    u32x4 a[8];
#pragma unroll
    for (int kt = 0; kt < 8; ++kt) a[kt] = *(const u32x4*)(habase + kt * 64);
    lds_barrier();  // all A-reads done before any h rewrite

    // gi prefetch j=0 (consumed after MFMAs)
    float p0[3][4];
#pragma unroll
    for (int r = 0; r < 4; ++r)
#pragma unroll
      for (int g = 0; g < 3; ++g)
        p0[g][r] = gload(gp, (size_t)(q * 4 + r) * 1536 + g * 256);

    f32x4 acc[2][3] = {};
#pragma unroll
    for (int kt = 0; kt < 6; ++kt)
#pragma unroll
      for (int j = 0; j < 2; ++j)
#pragma unroll
        for (int g = 0; g < 3; ++g)
          acc[j][g] = mfma16(a[kt], wv[j][g][kt], acc[j][g]);
#pragma unroll
    for (int kk = 0; kk < 2; ++kk) {
      u32x4 bf[2][3];
#pragma unroll
      for (int j = 0; j < 2; ++j)
#pragma unroll
        for (int g = 0; g < 3; ++g)
          bf[j][g] = *(const u32x4*)(
              wlds + (((w * 12 + (j * 3 + g) * 2 + kk) << 10) + lane * 16));
#pragma unroll
      for (int j = 0; j < 2; ++j)
#pragma unroll
        for (int g = 0; g < 3; ++g)
          acc[j][g] = mfma16(a[6 + kk], bf[j][g], acc[j][g]);
    }

    // gi prefetch j=1 (latency hides under j=0 gate math)
    float p1[3][4];
#pragma unroll
    for (int r = 0; r < 4; ++r)
#pragma unroll
      for (int g = 0; g < 3; ++g)
        p1[g][r] = gload(gp, (size_t)(q * 4 + r) * 1536 + g * 256 + 16);

    unsigned short* hls = (unsigned short*)hl;
#pragma unroll
    for (int r = 0; r < 4; ++r) {  // sample s = q*4+r ; C-row = q*4+reg
      const float rr0 = sigm2(p0[0][r] + acc[0][0][r]);
      const float zz0 = sigm2(p0[1][r] + acc[0][1][r]);
      const float nn0 = tanh2(__builtin_fmaf(rr0, acc[0][2][r] + bhn0, p0[2][r]));
      const float hv0 = __builtin_fmaf(zz0, h0[r] - nn0, nn0);
      h0[r] = hv0;
      const float rr1 = sigm2(p1[0][r] + acc[1][0][r]);
      const float zz1 = sigm2(p1[1][r] + acc[1][1][r]);
      const float nn1 = tanh2(__builtin_fmaf(rr1, acc[1][2][r] + bhn1, p1[2][r]));
      const float hv1 = __builtin_fmaf(zz1, h1[r] - nn1, nn1);
      h1[r] = hv1;
      const unsigned short hb0 = f2b(hv0), hb1 = f2b(hv1);
      hls[hw0 + r * 288] = hb0;
      hls[hw0 + r * 288 + 16] = hb1;
      hp[(size_t)(q * 4 + r) * 512] = hb0;
      hp[(size_t)(q * 4 + r) * 512 + 16] = hb1;
    }
    gp += gstep;
    hp += hstep;
    lds_barrier();  // h writes visible before next step's A-reads
  }
}

// ---------------------------------------------------------------------------
// LEGACY GRU (fallback if big dynamic LDS unsupported) — scaled-gate port.
template <typename GT>
__global__ __launch_bounds__(1024) void gru_layer_kernel(
    const GT* __restrict__ gi, const unsigned short* __restrict__ whh,
    const float* __restrict__ bhh, unsigned short* __restrict__ hout) {
  __shared__ __align__(16) unsigned short hbf[16][264];
  __shared__ __align__(16) float gh[16][780];
  const int tid = threadIdx.x;
  const int lane = tid & 63;
  const int wv = tid >> 6;
  const int dir = blockIdx.x & 1;
  const int sb = (blockIdx.x >> 1) * 16;
  const int j = tid & 255;
  const int si = tid >> 8;

  float hreg[4] = {0.f, 0.f, 0.f, 0.f};
#pragma unroll
  for (int i = 0; i < 4; ++i) hbf[si + i * 4][j] = 0;

  const float bh_n = SN * bhh[dir * 768 + 512 + j];

  const unsigned short* wl = whh + (size_t)dir * 768 * 256 +
                             (size_t)(wv * 48 + (lane & 15)) * 256 +
                             ((lane >> 4) * 8);
  const char* habase = (const char*)hbf + (lane & 15) * 528 + ((lane >> 4) << 4);
  const int srow = (lane >> 4) * 4;

  __syncthreads();

  for (int step = 0; step < 1000; ++step) {
    const int t = dir ? (999 - step) : step;
    float p_ir[4], p_iz[4], p_in[4];
#pragma unroll
    for (int i = 0; i < 4; ++i) {
      const int s = si + i * 4;
      const size_t gib = ((size_t)t * 64 + (sb + s)) * 1536 + dir * 768 + j;
      p_ir[i] = gload(gi, gib);
      p_iz[i] = gload(gi, gib + 256);
      p_in[i] = gload(gi, gib + 512);
    }
    u32x4 a[8];
#pragma unroll
    for (int kt = 0; kt < 8; ++kt) a[kt] = *(const u32x4*)(habase + kt * 64);
#pragma unroll
    for (int ntd = 0; ntd < 3; ++ntd) {
      f32x4 acc = {0.f, 0.f, 0.f, 0.f};
#pragma unroll
      for (int kt = 0; kt < 8; ++kt) {
        u32x4 bfrag = *(const u32x4*)(wl + ntd * (16 * 256) + kt * 32);
        acc = mfma16(a[kt], bfrag, acc);
      }
      const int gcol = (wv * 3 + ntd) * 16 + (lane & 15);
#pragma unroll
      for (int r = 0; r < 4; ++r) gh[srow + r][gcol] = acc[r];
    }
    __syncthreads();
#pragma unroll
    for (int i = 0; i < 4; ++i) {
      const int s = si + i * 4;
      const float r = sigm2(p_ir[i] + gh[s][j]);
      const float z = sigm2(p_iz[i] + gh[s][256 + j]);
      const float n = tanh2(__builtin_fmaf(r, gh[s][512 + j] + bh_n, p_in[i]));
      const float h = __builtin_fmaf(z, hreg[i] - n, n);
      hreg[i] = h;
      const unsigned short hb = f2b(h);
      hbf[s][j] = hb;
      hout[((size_t)t * 64 + (sb + s)) * 512 + dir * 256 + j] = hb;
    }
    __syncthreads();
  }
}

// ---------------------------------------------------------------------------
__global__ void prefix_kernel(const int* __restrict__ raw,
                              int* __restrict__ pref, int* __restrict__ lens) {
  if (threadIdx.x == 0) {
    const int stride = (raw[1] == 0 && raw[3] == 0 && raw[5] == 0) ? 2 : 1;
    int a = 0;
    for (int b = 0; b < 64; ++b) {
      const int L = raw[b * stride];
      pref[b] = a;
      lens[b] = L;
      a += L;
    }
  }
}

__global__ __launch_bounds__(256) void fc_kernel(
    const unsigned short* __restrict__ h2, const unsigned short* __restrict__ fcw,
    const float* __restrict__ fcb, const int* __restrict__ lens,
    const int* __restrict__ pref, float* __restrict__ out) {
  __shared__ __align__(16) unsigned short hrow[4][512];
  const int b = blockIdx.y;
  const int sub = threadIdx.x >> 6, lane = threadIdx.x & 63;
  const int t = blockIdx.x * 4 + sub;
  *(u32x4*)&hrow[sub][lane * 8] =
      *(const u32x4*)&h2[((size_t)t * 64 + b) * 512 + lane * 8];
  __syncthreads();
  const int len = lens[b];
  if (lane < 61 && t < len) {
    float acc = fcb[lane];
    const unsigned short* wr = fcw + (size_t)lane * 512;
#pragma unroll 4
    for (int k = 0; k < 512; k += 8) {
      u32x4 w4 = *(const u32x4*)(wr + k);
      u32x4 h4 = *(const u32x4*)(&hrow[sub][k]);
#pragma unroll
      for (int qq = 0; qq < 4; ++qq) {
        acc += __uint_as_float(w4[qq] << 16) * __uint_as_float(h4[qq] << 16);
        acc += __uint_as_float(w4[qq] & 0xffff0000u) * __uint_as_float(h4[qq] & 0xffff0000u);
      }
    }
    out[((size_t)pref[b] + t) * 61 + lane] = acc;
  }
}

// ---------------------------------------------------------------------------
template <typename GT>
static void run_pipeline(const float* batch, const int* lengths_raw,
                         const float* w_ih_l0, const float* w_hh_l0,
                         const float* b_ih_l0, const float* b_hh_l0,
                         const float* w_ih_l1, const float* w_hh_l1,
                         const float* b_ih_l1, const float* b_hh_l1,
                         const float* fc_w, const float* fc_b, float* out,
                         char* ws, hipStream_t stream) {
  size_t off = 0;
  auto alloc = [&](size_t bytes) -> char* {
    char* p = ws + off;
    off += (bytes + 255) & ~(size_t)255;
    return p;
  };
  char* pool = alloc((size_t)64000 * 512 * 2);  // xb/h1/h2 liveness-disjoint
  unsigned short* xb = (unsigned short*)pool;
  unsigned short* h1 = (unsigned short*)pool;
  unsigned short* h2 = (unsigned short*)pool;
  GT*             gi   = (GT*)alloc((size_t)64000 * 1536 * sizeof(GT));
  unsigned short* wih0 = (unsigned short*)alloc((size_t)1536 * 320 * 2);
  unsigned short* wih1 = (unsigned short*)alloc((size_t)1536 * 512 * 2);
  unsigned short* whh0 = (unsigned short*)alloc((size_t)1536 * 256 * 2);
  unsigned short* whh1 = (unsigned short*)alloc((size_t)1536 * 256 * 2);
  unsigned short* fcwb = (unsigned short*)alloc((size_t)61 * 512 * 2);
  float*          fb0  = (float*)alloc(1536 * 4);
  float*          fb1  = (float*)alloc(1536 * 4);
  int*            pref = (int*)alloc(256);
  int*            lens = (int*)alloc(256);

  auto castw = [&](const float* s, unsigned short* d, int n, int in_dim) {
    cast_w_kernel<<<dim3((n + 255) / 256), dim3(256), 0, stream>>>(s, d, n, in_dim);
  };
  castw(w_ih_l0, wih0, 2 * 768 * 320, 320);
  castw(w_hh_l0, whh0, 2 * 768 * 256, 256);
  castw(w_ih_l1, wih1, 2 * 768 * 512, 512);
  castw(w_hh_l1, whh1, 2 * 768 * 256, 256);
  cast_bf16_kernel<<<dim3((61 * 512 + 255) / 256), dim3(256), 0, stream>>>(
      fc_w, fcwb, 61 * 512);
  bias_fuse_kernel<<<dim3(6), dim3(256), 0, stream>>>(b_ih_l0, b_hh_l0, fb0);
  bias_fuse_kernel<<<dim3(6), dim3(256), 0, stream>>>(b_ih_l1, b_hh_l1, fb1);

  transpose_x_kernel<<<dim3(1000, 64), dim3(320), 0, stream>>>(batch, xb);

  const int GRU_LDS = 98304 + 9216;  // 107520 B
  const bool big_lds =
      hipFuncSetAttribute(reinterpret_cast<const void*>(gru_fast_kernel<GT>),
                          hipFuncAttributeMaxDynamicSharedMemorySize,
                          GRU_LDS) == hipSuccess;

  auto gru = [&](GT* g, unsigned short* w, const float* b, unsigned short* h) {
    if (big_lds)
      gru_fast_kernel<GT><<<dim3(8), dim3(512), GRU_LDS, stream>>>(g, w, b, h);
    else
      gru_layer_kernel<GT><<<dim3(8), dim3(1024), 0, stream>>>(g, w, b, h);
  };

  gemm_bt_kernel<GT><<<dim3(500, 12), dim3(256), 0, stream>>>(
      xb, wih0, fb0, gi, 64000, 1536, 320);
  gru(gi, whh0, b_hh_l0, h1);
  gemm_bt_kernel<GT><<<dim3(500, 12), dim3(256), 0, stream>>>(
      h1, wih1, fb1, gi, 64000, 1536, 512);
  gru(gi, whh1, b_hh_l1, h2);

  prefix_kernel<<<dim3(1), dim3(64), 0, stream>>>(lengths_raw, pref, lens);
  fc_kernel<<<dim3(250, 64), dim3(256), 0, stream>>>(h2, fcwb, fc_b, lens, pref, out);
}

extern "C" void kernel_launch(void* const* d_in, const int* in_sizes, int n_in,
                              void* d_out, int out_size, void* d_ws, size_t ws_size,
                              hipStream_t stream) {
  (void)in_sizes; (void)n_in; (void)out_size;
  const float* batch   = (const float*)d_in[0];
  const int*   lengths = (const int*)d_in[1];
  const float* w_ih_l0 = (const float*)d_in[2];
  const float* w_hh_l0 = (const float*)d_in[3];
  const float* b_ih_l0 = (const float*)d_in[4];
  const float* b_hh_l0 = (const float*)d_in[5];
  const float* w_ih_l1 = (const float*)d_in[6];
  const float* w_hh_l1 = (const float*)d_in[7];
  const float* b_ih_l1 = (const float*)d_in[8];
  const float* b_hh_l1 = (const float*)d_in[9];
  const float* fc_w    = (const float*)d_in[10];
  const float* fc_b    = (const float*)d_in[11];
  float* out = (float*)d_out;
  char* ws = (char*)d_ws;

  const size_t NEED_FP32 = 470000000ull;  // gi fp32 path peak
  if (ws_size >= NEED_FP32) {
    run_pipeline<float>(batch, lengths, w_ih_l0, w_hh_l0, b_ih_l0, b_hh_l0,
                        w_ih_l1, w_hh_l1, b_ih_l1, b_hh_l1, fc_w, fc_b, out,
                        ws, stream);
  } else {
    run_pipeline<unsigned short>(batch, lengths, w_ih_l0, w_hh_l0, b_ih_l0,
                                 b_hh_l0, w_ih_l1, w_hh_l1, b_ih_l1, b_hh_l1,
                                 fc_w, fc_b, out, ws, stream);
  }
}